// Round 5
// baseline (115.495 us; speedup 1.0000x reference)
//
#include <hip/hip_runtime.h>

// out[p] = max(0, segment_max over rows n with idx[n]==p of (feats[n].W + b))
//
// feats: [N][32] fp32, W: [1][32] fp32, b: [1] fp32, idx: [N] int32, out: [P] fp32.
//
// Memory-bound streaming. Each wave-iteration handles a 64-row super-group
// (8 KiB contiguous): 8 independent nontemporal float4 loads per lane (MLP=8),
// 8-lane shuffle-tree per row-dot. Every lane in an 8-lane group then holds
// all 8 k-dots; lane l selects dot k=l&7 (cndmask tree, compile-time indices)
// and owns row (l>>3)+8*(l&7) -- a permutation of 0..63 -- so the epilogue is
// ONE coalesced idx dword load + ONE atomic instruction with all 64 lanes
// active (no divergent sub==0 branch). Segment max via integer atomicMax on
// positive-float bit patterns (out pre-zeroed; r <= 0 never beats the floor).

typedef float f32x4 __attribute__((ext_vector_type(4)));

__global__ __launch_bounds__(256, 4) void miniNN_seglinmax_kernel(
    const f32x4* __restrict__ feats4,    // N*8 float4
    const float* __restrict__ W,         // 32 floats
    const float* __restrict__ b,         // 1 float
    const int*   __restrict__ idx,       // N int32
    int*         __restrict__ out_i,     // P floats viewed as int (pre-zeroed)
    int          n_rows)
{
    const int l    = threadIdx.x & 63;
    const int gwid = blockIdx.x * (blockDim.x >> 6) + (threadIdx.x >> 6);
    const int nw   = gridDim.x * (blockDim.x >> 6);

    const f32x4 wv  = ((const f32x4*)W)[l & 7];
    const float bias = b[0];

    // lane l owns row (l>>3) + 8*(l&7) within each 64-row super-group
    const int myrow = (l >> 3) + ((l & 7) << 3);

    const int nsuper = n_rows >> 6;      // 64 rows per super-group
    for (int sg = gwid; sg < nsuper; sg += nw) {
        // 8 KiB contiguous per wave-iteration; 8 loads in flight per lane.
        const f32x4* p = feats4 + (sg << 9) + l;
        const f32x4 v0 = __builtin_nontemporal_load(p);
        const f32x4 v1 = __builtin_nontemporal_load(p + 64);
        const f32x4 v2 = __builtin_nontemporal_load(p + 128);
        const f32x4 v3 = __builtin_nontemporal_load(p + 192);
        const f32x4 v4 = __builtin_nontemporal_load(p + 256);
        const f32x4 v5 = __builtin_nontemporal_load(p + 320);
        const f32x4 v6 = __builtin_nontemporal_load(p + 384);
        const f32x4 v7 = __builtin_nontemporal_load(p + 448);

        float s[8];
        s[0] = v0.x * wv.x + v0.y * wv.y + v0.z * wv.z + v0.w * wv.w;
        s[1] = v1.x * wv.x + v1.y * wv.y + v1.z * wv.z + v1.w * wv.w;
        s[2] = v2.x * wv.x + v2.y * wv.y + v2.z * wv.z + v2.w * wv.w;
        s[3] = v3.x * wv.x + v3.y * wv.y + v3.z * wv.z + v3.w * wv.w;
        s[4] = v4.x * wv.x + v4.y * wv.y + v4.z * wv.z + v4.w * wv.w;
        s[5] = v5.x * wv.x + v5.y * wv.y + v5.z * wv.z + v5.w * wv.w;
        s[6] = v6.x * wv.x + v6.y * wv.y + v6.z * wv.z + v6.w * wv.w;
        s[7] = v7.x * wv.x + v7.y * wv.y + v7.z * wv.z + v7.w * wv.w;

        #pragma unroll
        for (int k = 0; k < 8; ++k) {
            s[k] += __shfl_xor(s[k], 1);
            s[k] += __shfl_xor(s[k], 2);
            s[k] += __shfl_xor(s[k], 4);
        }

        // lane l picks dot k = l&7 (all lanes of a group hold identical s[k])
        const bool b0 = (l & 1) != 0;
        const bool b1 = (l & 2) != 0;
        const bool b2 = (l & 4) != 0;
        const float t0 = b0 ? s[1] : s[0];
        const float t1 = b0 ? s[3] : s[2];
        const float t2 = b0 ? s[5] : s[4];
        const float t3 = b0 ? s[7] : s[6];
        const float u0 = b1 ? t1 : t0;
        const float u1 = b1 ? t3 : t2;
        const float dot = b2 ? u1 : u0;

        // one coalesced idx load (permutation within a 256B window) and one
        // atomic instruction with all 64 lanes active
        const int i  = __builtin_nontemporal_load(idx + (sg << 6) + myrow);
        const float r = dot + bias;
        if (r > 0.0f) atomicMax(out_i + i, __float_as_int(r));
    }

    // Tail rows (n_rows % 64 != 0) — scalar path, negligible work.
    const int tail_start = nsuper << 6;
    const int gtid = blockIdx.x * blockDim.x + threadIdx.x;
    const int row  = tail_start + gtid;
    if (row < n_rows) {
        const float* f = (const float*)feats4 + (long long)row * 32;
        float r = bias;
        #pragma unroll
        for (int k = 0; k < 32; ++k) r += f[k] * W[k];
        if (r > 0.0f) atomicMax(out_i + idx[row], __float_as_int(r));
    }
}

extern "C" void kernel_launch(void* const* d_in, const int* in_sizes, int n_in,
                              void* d_out, int out_size, void* d_ws, size_t ws_size,
                              hipStream_t stream) {
    const float* feats = (const float*)d_in[0];
    const float* W     = (const float*)d_in[1];
    const float* b     = (const float*)d_in[2];
    const int*   idx   = (const int*)d_in[3];
    const int n_rows   = in_sizes[0] / 32;

    // Zero output: handles empty segments (segment_max -> -inf, then
    // max(.,0) = 0) and is the identity for the positive-float atomicMax.
    (void)hipMemsetAsync(d_out, 0, (size_t)out_size * sizeof(float), stream);

    // Balanced grid: waves = blocks*4; minimize total wave-iteration slots
    // (waves * iters) over the 64-row super-groups. For nsuper=62500 picks
    // 1954 blocks: 7816 waves x 8 iters = 62528 (99.96% utilization).
    const int nsuper = n_rows >> 6;
    int best_blocks = 2048;
    long long best_cost = 0x7fffffffffffffffLL;
    for (int blk = 256; blk <= 2048; ++blk) {
        const long long waves = (long long)blk * 4;
        const long long iters = (nsuper + waves - 1) / waves;
        const long long cost  = waves * iters;
        if (cost < best_cost || (cost == best_cost && blk > best_blocks)) {
            best_cost = cost; best_blocks = blk;
        }
    }

    miniNN_seglinmax_kernel<<<best_blocks, 256, 0, stream>>>(
        (const f32x4*)feats, W, b, idx, (int*)d_out, n_rows);
}